// Round 1
// baseline (245.289 us; speedup 1.0000x reference)
//
#include <hip/hip_runtime.h>

// B=2, T=2048, C=1024, H=16, HD=64, SCALE=0.125
// Pipeline: cvt x->bf16; transpose W->bf16 [N][K]; GEMM1 qkv=x@Wqkv (bf16 out);
// transpose V part -> vT; flash attn -> att (bf16); GEMM2 out = att@Wp + bp (f32).

typedef __attribute__((ext_vector_type(8))) short shortx8;
typedef __attribute__((ext_vector_type(8))) unsigned short ushortx8;
typedef __attribute__((ext_vector_type(4))) float f32x4;

#define MFMA16(a, b, c) __builtin_amdgcn_mfma_f32_16x16x32_bf16((a), (b), (c), 0, 0, 0)

__device__ __forceinline__ unsigned short f2bf(float f) {
  union { float f; unsigned u; } v; v.f = f;
  unsigned r = v.u + 0x7fffu + ((v.u >> 16) & 1u);  // RNE; inputs finite
  return (unsigned short)(r >> 16);
}

__device__ __forceinline__ void gload16(const void* g, void* l) {
  __builtin_amdgcn_global_load_lds(
      (const __attribute__((address_space(1))) void*)g,
      (__attribute__((address_space(3))) void*)l, 16, 0, 0);
}

// ---------------- conversions ----------------
__global__ __launch_bounds__(256) void cvt_x(const float* __restrict__ x,
                                             unsigned short* __restrict__ xb, int n4) {
  int i = blockIdx.x * 256 + threadIdx.x;
  if (i < n4) {
    float4 v = ((const float4*)x)[i];
    unsigned short* o = xb + (size_t)i * 4;
    o[0] = f2bf(v.x); o[1] = f2bf(v.y); o[2] = f2bf(v.z); o[3] = f2bf(v.w);
  }
}

// W [1024][1024] f32 -> WT [1024][1024] bf16 (WT[n][k] = W[k][n])
__global__ __launch_bounds__(256) void transpose_w(const float* __restrict__ src,
                                                   unsigned short* __restrict__ dst) {
  __shared__ float tile[32][33];
  const int bx = blockIdx.x * 32, by = blockIdx.y * 32;
  const int tx = threadIdx.x & 31, ty = threadIdx.x >> 5;  // 32 x 8
  #pragma unroll
  for (int i = 0; i < 32; i += 8)
    tile[ty + i][tx] = src[(size_t)(by + ty + i) * 1024 + bx + tx];
  __syncthreads();
  #pragma unroll
  for (int i = 0; i < 32; i += 8)
    dst[(size_t)(bx + ty + i) * 1024 + by + tx] = f2bf(tile[tx][ty + i]);
}

// V part of qkv [4096][cols 2048..3071] bf16 -> vT [1024][4096] bf16
__global__ __launch_bounds__(256) void transpose_v(const unsigned short* __restrict__ qkv,
                                                   unsigned short* __restrict__ vT) {
  __shared__ unsigned short tile[64][65];  // pad 65: 2-way banks both directions
  const int bx = blockIdx.x * 64;  // hd dim (0..1023)
  const int by = blockIdx.y * 64;  // row dim (0..4095)
  const int t = threadIdx.x;
  const int r = t >> 3, c8 = (t & 7) << 3;
  #pragma unroll
  for (int i = 0; i < 2; ++i) {
    ushortx8 v = *(const ushortx8*)&qkv[(size_t)(by + i * 32 + r) * 3072 + 2048 + bx + c8];
    #pragma unroll
    for (int j = 0; j < 8; ++j) tile[i * 32 + r][c8 + j] = v[j];
  }
  __syncthreads();
  #pragma unroll
  for (int i = 0; i < 2; ++i) {
    const int dr = i * 32 + r;  // = source col index
    ushortx8 o;
    #pragma unroll
    for (int j = 0; j < 8; ++j) o[j] = tile[c8 + j][dr];
    *(ushortx8*)&vT[(size_t)(bx + dr) * 4096 + by + c8] = o;
  }
}

// ---------------- GEMM: C[M,N] = A[M,K] @ BT[N,K]^T ----------------
// 128x128 tile, BK=32, 4 waves (2x2), each wave 64x64 = 4x4 of 16x16x32 MFMA.
__global__ __launch_bounds__(256) void gemm_bt(
    const unsigned short* __restrict__ A, const unsigned short* __restrict__ BT,
    unsigned short* __restrict__ Cb, float* __restrict__ Cf,
    const float* __restrict__ bias, int M, int N, int K) {
  __shared__ unsigned short As[128 * 32];
  __shared__ unsigned short Bs[128 * 32];
  const int tid = threadIdx.x;
  const int lane = tid & 63, w = tid >> 6;
  const int wr = w >> 1, wc = w & 1;
  const int brow = blockIdx.y << 7, bcol = blockIdx.x << 7;

  f32x4 z = {0.f, 0.f, 0.f, 0.f};
  f32x4 acc[4][4];
  #pragma unroll
  for (int m = 0; m < 4; ++m)
    #pragma unroll
    for (int n = 0; n < 4; ++n) acc[m][n] = z;

  // staging: thread t -> row t/4 (+64 for iter 2), elem col (t%4)*8; lds = wave base + lane*16B
  const int srow = tid >> 2;
  const int scol = (tid & 3) << 3;
  const unsigned short* Ap = A + (size_t)(brow + srow) * K + scol;
  const unsigned short* Bp = BT + (size_t)(bcol + srow) * K + scol;
  unsigned short* AsW = &As[w * 512];
  unsigned short* BsW = &Bs[w * 512];
  const size_t rowK64 = (size_t)64 * K;

  for (int k0 = 0; k0 < K; k0 += 32) {
    gload16(Ap + k0, AsW);
    gload16(Ap + rowK64 + k0, AsW + 2048);
    gload16(Bp + k0, BsW);
    gload16(Bp + rowK64 + k0, BsW + 2048);
    __syncthreads();
    shortx8 af[4], bf[4];
    const int koff = (lane >> 4) << 3;
    const int ar = (wr << 6) + (lane & 15);
    const int br = (wc << 6) + (lane & 15);
    #pragma unroll
    for (int m = 0; m < 4; ++m) af[m] = *(const shortx8*)&As[(ar + m * 16) * 32 + koff];
    #pragma unroll
    for (int n = 0; n < 4; ++n) bf[n] = *(const shortx8*)&Bs[(br + n * 16) * 32 + koff];
    #pragma unroll
    for (int m = 0; m < 4; ++m)
      #pragma unroll
      for (int n = 0; n < 4; ++n) acc[m][n] = MFMA16(af[m], bf[n], acc[m][n]);
    __syncthreads();
  }

  const int r0 = (lane >> 4) << 2;
  const int c0 = lane & 15;
  if (Cb) {
    #pragma unroll
    for (int m = 0; m < 4; ++m)
      #pragma unroll
      for (int n = 0; n < 4; ++n)
        #pragma unroll
        for (int j = 0; j < 4; ++j) {
          const size_t row = brow + (wr << 6) + m * 16 + r0 + j;
          const size_t col = bcol + (wc << 6) + n * 16 + c0;
          Cb[row * N + col] = f2bf(acc[m][n][j]);
        }
  } else {
    #pragma unroll
    for (int m = 0; m < 4; ++m)
      #pragma unroll
      for (int n = 0; n < 4; ++n)
        #pragma unroll
        for (int j = 0; j < 4; ++j) {
          const size_t row = brow + (wr << 6) + m * 16 + r0 + j;
          const size_t col = bcol + (wc << 6) + n * 16 + c0;
          Cf[row * N + col] = acc[m][n][j] + bias[col];
        }
  }
}

// ---------------- flash attention ----------------
// Block: 256 thr = 4 waves; one (b,h,qtile of 64). Wave owns 16 q rows.
// K tile [64 kv][64 hd], Vt tile [64 hd][64 kv] in LDS, XOR-swizzled 16B chunks
// (swizzle applied on the GLOBAL source so global_load_lds linear dest works; rule #21).
__global__ __launch_bounds__(256) void attn_fwd(
    const unsigned short* __restrict__ qkv, const unsigned short* __restrict__ vT,
    unsigned short* __restrict__ attn_out) {
  __shared__ unsigned short Ks[64 * 64];
  __shared__ unsigned short Vt[64 * 64];
  __shared__ unsigned short Ps[4][16 * 32];

  const int tid = threadIdx.x;
  const int lane = tid & 63;
  const int w = tid >> 6;
  const int qt = blockIdx.x, h = blockIdx.y, b = blockIdx.z;
  const int q0 = qt * 64;
  const int qbase = q0 + w * 16;

  // Q fragments (A operand: row = lane%16, k = (lane/16)*8..+7), held in regs
  const int qr = qbase + (lane & 15);
  const unsigned short* qp = qkv + (size_t)(b * 2048 + qr) * 3072 + h * 64 + ((lane >> 4) << 3);
  const shortx8 qf0 = *(const shortx8*)qp;
  const shortx8 qf1 = *(const shortx8*)(qp + 32);

  f32x4 z = {0.f, 0.f, 0.f, 0.f};
  f32x4 acc[4];
  #pragma unroll
  for (int c = 0; c < 4; ++c) acc[c] = z;
  float m_run[4], l_run[4];
  #pragma unroll
  for (int j = 0; j < 4; ++j) { m_run[j] = -__builtin_inff(); l_run[j] = 0.f; }

  // staging: thread t -> row t/8 (+32 iter2), 16B chunk ((t%8) ^ (row&7)) of that row
  const int srow = tid >> 3;
  const int schunk = ((tid & 7) ^ (srow & 7)) << 3;
  const unsigned short* kbase = qkv + (size_t)(b * 2048 + srow) * 3072 + 1024 + h * 64 + schunk;
  const unsigned short* vbase = vT + (size_t)(h * 64 + srow) * 4096 + b * 2048 + schunk;
  unsigned short* KsW = &Ks[w * 512];
  unsigned short* VtW = &Vt[w * 512];

  for (int kvt = 0; kvt <= qt; ++kvt) {
    const int kv0 = kvt * 64;
    gload16(kbase + (size_t)kv0 * 3072, KsW);
    gload16(kbase + (size_t)(kv0 + 32) * 3072, KsW + 2048);
    gload16(vbase + kv0, VtW);
    gload16(vbase + (size_t)32 * 4096 + kv0, VtW + 2048);
    __syncthreads();

    #pragma unroll
    for (int ch = 0; ch < 2; ++ch) {
      // S = Q @ K^T for 16 q x 32 kv (two 16-col halves)
      f32x4 s[2]; s[0] = z; s[1] = z;
      const int swz = lane & 7;
      #pragma unroll
      for (int h2 = 0; h2 < 2; ++h2) {
        const int kvloc = ch * 32 + h2 * 16 + (lane & 15);
        shortx8 kb0 = *(const shortx8*)&Ks[kvloc * 64 + ((((lane >> 4)) ^ swz) << 3)];
        shortx8 kb1 = *(const shortx8*)&Ks[kvloc * 64 + (((4 + (lane >> 4)) ^ swz) << 3)];
        s[h2] = MFMA16(qf0, kb0, s[h2]);
        s[h2] = MFMA16(qf1, kb1, s[h2]);
      }
      // scale + causal mask; C/D layout: row=(lane>>4)*4+j, col=lane&15
      const int colb = kv0 + ch * 32 + (lane & 15);
      const int qrow0 = qbase + ((lane >> 4) << 2);
      float sv[2][4];
      #pragma unroll
      for (int h2 = 0; h2 < 2; ++h2)
        #pragma unroll
        for (int j = 0; j < 4; ++j) {
          float v = s[h2][j] * 0.125f;
          sv[h2][j] = (colb + h2 * 16 <= qrow0 + j) ? v : -__builtin_inff();
        }
      // row max over 16 lanes of the group
      float rmax[4];
      #pragma unroll
      for (int j = 0; j < 4; ++j) rmax[j] = fmaxf(sv[0][j], sv[1][j]);
      #pragma unroll
      for (int off = 1; off < 16; off <<= 1)
        #pragma unroll
        for (int j = 0; j < 4; ++j) rmax[j] = fmaxf(rmax[j], __shfl_xor(rmax[j], off));
      float pj[2][4], alpha[4], rsum[4];
      #pragma unroll
      for (int j = 0; j < 4; ++j) {
        const float nm = fmaxf(m_run[j], rmax[j]);
        const bool ninf = (nm == -__builtin_inff());
        alpha[j] = ninf ? 1.f : __expf(m_run[j] - nm);  // m_run=-inf -> exp(-inf)=0 ok
        pj[0][j] = ninf ? 0.f : __expf(sv[0][j] - nm);
        pj[1][j] = ninf ? 0.f : __expf(sv[1][j] - nm);
        m_run[j] = nm;
        rsum[j] = pj[0][j] + pj[1][j];
        #pragma unroll
        for (int c = 0; c < 4; ++c) acc[c][j] *= alpha[j];
      }
      #pragma unroll
      for (int off = 1; off < 16; off <<= 1)
        #pragma unroll
        for (int j = 0; j < 4; ++j) rsum[j] += __shfl_xor(rsum[j], off);
      #pragma unroll
      for (int j = 0; j < 4; ++j) l_run[j] = l_run[j] * alpha[j] + rsum[j];

      // P (C/D layout) -> per-wave LDS -> A-operand layout
      #pragma unroll
      for (int h2 = 0; h2 < 2; ++h2)
        #pragma unroll
        for (int j = 0; j < 4; ++j)
          Ps[w][(((lane >> 4) << 2) + j) * 32 + h2 * 16 + (lane & 15)] = f2bf(pj[h2][j]);
      __builtin_amdgcn_sched_barrier(0);  // keep ds_write before ds_read (same-wave DS is in-order)
      const shortx8 pf = *(const shortx8*)&Ps[w][(lane & 15) * 32 + ((lane >> 4) << 3)];
      #pragma unroll
      for (int c = 0; c < 4; ++c) {
        shortx8 vb = *(const shortx8*)&Vt[(c * 16 + (lane & 15)) * 64 +
                                          ((((ch << 2) + (lane >> 4)) ^ swz) << 3)];
        acc[c] = MFMA16(pf, vb, acc[c]);
      }
    }
    __syncthreads();
  }

  #pragma unroll
  for (int j = 0; j < 4; ++j) {
    const float inv = 1.f / l_run[j];
    const int qrow = qbase + ((lane >> 4) << 2) + j;
    unsigned short* op = attn_out + (size_t)(b * 2048 + qrow) * 1024 + h * 64 + (lane & 15);
    #pragma unroll
    for (int c = 0; c < 4; ++c) op[c * 16] = f2bf(acc[c][j] * inv);
  }
}

// ---------------- launch ----------------
extern "C" void kernel_launch(void* const* d_in, const int* in_sizes, int n_in,
                              void* d_out, int out_size, void* d_ws, size_t ws_size,
                              hipStream_t stream) {
  const float* x  = (const float*)d_in[0];
  const float* Wq = (const float*)d_in[1];
  const float* Wk = (const float*)d_in[2];
  const float* Wv = (const float*)d_in[3];
  const float* Wp = (const float*)d_in[4];
  const float* bp = (const float*)d_in[5];

  char* ws = (char*)d_ws;
  unsigned short* xb    = (unsigned short*)(ws);                        //  8 MB [4096][1024]
  unsigned short* wqkvT = (unsigned short*)(ws + (size_t)8  * 1048576); //  6 MB [3072][1024]
  unsigned short* wpT   = (unsigned short*)(ws + (size_t)14 * 1048576); //  2 MB [1024][1024]
  unsigned short* qkv   = (unsigned short*)(ws + (size_t)16 * 1048576); // 24 MB [4096][3072]
  unsigned short* vT    = (unsigned short*)(ws + (size_t)40 * 1048576); //  8 MB [1024][4096]
  unsigned short* att   = (unsigned short*)(ws + (size_t)48 * 1048576); //  8 MB [4096][1024]

  cvt_x<<<dim3(4096), dim3(256), 0, stream>>>(x, xb, 1048576);
  transpose_w<<<dim3(32, 32), dim3(256), 0, stream>>>(Wq, wqkvT);
  transpose_w<<<dim3(32, 32), dim3(256), 0, stream>>>(Wk, wqkvT + (size_t)1048576);
  transpose_w<<<dim3(32, 32), dim3(256), 0, stream>>>(Wv, wqkvT + (size_t)2097152);
  transpose_w<<<dim3(32, 32), dim3(256), 0, stream>>>(Wp, wpT);
  gemm_bt<<<dim3(24, 32), dim3(256), 0, stream>>>(xb, wqkvT, qkv, nullptr, nullptr,
                                                  4096, 3072, 1024);
  transpose_v<<<dim3(16, 64), dim3(256), 0, stream>>>(qkv, vT);
  attn_fwd<<<dim3(32, 16, 2), dim3(256), 0, stream>>>(qkv, vT, att);
  gemm_bt<<<dim3(8, 32), dim3(256), 0, stream>>>(att, wpT, nullptr, (float*)d_out, bp,
                                                 4096, 1024, 1024);
}

// Round 2
// 144.464 us; speedup vs baseline: 1.6979x; 1.6979x over previous
//
#include <hip/hip_runtime.h>

// B=2, T=2048, C=1024, H=16, HD=64, SCALE=0.125
// Pipeline: cvt x->bf16; transpose W->bf16 [N][K]; GEMM1 qkv=x@Wqkv (bf16 out);
// transpose V part -> vT; flash attn (swapped-QK^T, O^T accum, paired q-tiles,
// double-buffered K/V) -> att (bf16); GEMM2 out = att@Wp + bp (f32).

typedef __attribute__((ext_vector_type(8))) short shortx8;
typedef __attribute__((ext_vector_type(4))) short shortx4;
typedef __attribute__((ext_vector_type(8))) unsigned short ushortx8;
typedef __attribute__((ext_vector_type(4))) float f32x4;

#define MFMA16(a, b, c) __builtin_amdgcn_mfma_f32_16x16x32_bf16((a), (b), (c), 0, 0, 0)

__device__ __forceinline__ unsigned short f2bf(float f) {
  union { float f; unsigned u; } v; v.f = f;
  unsigned r = v.u + 0x7fffu + ((v.u >> 16) & 1u);  // RNE; inputs finite
  return (unsigned short)(r >> 16);
}

__device__ __forceinline__ void gload16(const void* g, void* l) {
  __builtin_amdgcn_global_load_lds(
      (const __attribute__((address_space(1))) void*)g,
      (__attribute__((address_space(3))) void*)l, 16, 0, 0);
}

// ---------------- conversions ----------------
__global__ __launch_bounds__(256) void cvt_x(const float* __restrict__ x,
                                             unsigned short* __restrict__ xb, int n4) {
  int i = blockIdx.x * 256 + threadIdx.x;
  if (i < n4) {
    float4 v = ((const float4*)x)[i];
    unsigned short* o = xb + (size_t)i * 4;
    o[0] = f2bf(v.x); o[1] = f2bf(v.y); o[2] = f2bf(v.z); o[3] = f2bf(v.w);
  }
}

// W [1024][1024] f32 -> WT [1024][1024] bf16 (WT[n][k] = W[k][n])
__global__ __launch_bounds__(256) void transpose_w(const float* __restrict__ src,
                                                   unsigned short* __restrict__ dst) {
  __shared__ float tile[32][33];
  const int bx = blockIdx.x * 32, by = blockIdx.y * 32;
  const int tx = threadIdx.x & 31, ty = threadIdx.x >> 5;  // 32 x 8
  #pragma unroll
  for (int i = 0; i < 32; i += 8)
    tile[ty + i][tx] = src[(size_t)(by + ty + i) * 1024 + bx + tx];
  __syncthreads();
  #pragma unroll
  for (int i = 0; i < 32; i += 8)
    dst[(size_t)(bx + ty + i) * 1024 + by + tx] = f2bf(tile[tx][ty + i]);
}

// V part of qkv [4096][cols 2048..3071] bf16 -> vT [1024][4096] bf16
__global__ __launch_bounds__(256) void transpose_v(const unsigned short* __restrict__ qkv,
                                                   unsigned short* __restrict__ vT) {
  __shared__ unsigned short tile[64][65];
  const int bx = blockIdx.x * 64;  // hd dim (0..1023)
  const int by = blockIdx.y * 64;  // row dim (0..4095)
  const int t = threadIdx.x;
  const int r = t >> 3, c8 = (t & 7) << 3;
  #pragma unroll
  for (int i = 0; i < 2; ++i) {
    ushortx8 v = *(const ushortx8*)&qkv[(size_t)(by + i * 32 + r) * 3072 + 2048 + bx + c8];
    #pragma unroll
    for (int j = 0; j < 8; ++j) tile[i * 32 + r][c8 + j] = v[j];
  }
  __syncthreads();
  #pragma unroll
  for (int i = 0; i < 2; ++i) {
    const int dr = i * 32 + r;
    ushortx8 o;
    #pragma unroll
    for (int j = 0; j < 8; ++j) o[j] = tile[c8 + j][dr];
    *(ushortx8*)&vT[(size_t)(bx + dr) * 4096 + by + c8] = o;
  }
}

// ---------------- GEMM: C[M,N] = A[M,K] @ BT[N,K]^T ----------------
__global__ __launch_bounds__(256) void gemm_bt(
    const unsigned short* __restrict__ A, const unsigned short* __restrict__ BT,
    unsigned short* __restrict__ Cb, float* __restrict__ Cf,
    const float* __restrict__ bias, int M, int N, int K) {
  __shared__ unsigned short As[128 * 32];
  __shared__ unsigned short Bs[128 * 32];
  const int tid = threadIdx.x;
  const int lane = tid & 63, w = tid >> 6;
  const int wr = w >> 1, wc = w & 1;
  const int brow = blockIdx.y << 7, bcol = blockIdx.x << 7;

  f32x4 z = {0.f, 0.f, 0.f, 0.f};
  f32x4 acc[4][4];
  #pragma unroll
  for (int m = 0; m < 4; ++m)
    #pragma unroll
    for (int n = 0; n < 4; ++n) acc[m][n] = z;

  const int srow = tid >> 2;
  const int scol = (tid & 3) << 3;
  const unsigned short* Ap = A + (size_t)(brow + srow) * K + scol;
  const unsigned short* Bp = BT + (size_t)(bcol + srow) * K + scol;
  unsigned short* AsW = &As[w * 512];
  unsigned short* BsW = &Bs[w * 512];
  const size_t rowK64 = (size_t)64 * K;

  for (int k0 = 0; k0 < K; k0 += 32) {
    gload16(Ap + k0, AsW);
    gload16(Ap + rowK64 + k0, AsW + 2048);
    gload16(Bp + k0, BsW);
    gload16(Bp + rowK64 + k0, BsW + 2048);
    __syncthreads();
    shortx8 af[4], bf[4];
    const int koff = (lane >> 4) << 3;
    const int ar = (wr << 6) + (lane & 15);
    const int br = (wc << 6) + (lane & 15);
    #pragma unroll
    for (int m = 0; m < 4; ++m) af[m] = *(const shortx8*)&As[(ar + m * 16) * 32 + koff];
    #pragma unroll
    for (int n = 0; n < 4; ++n) bf[n] = *(const shortx8*)&Bs[(br + n * 16) * 32 + koff];
    #pragma unroll
    for (int m = 0; m < 4; ++m)
      #pragma unroll
      for (int n = 0; n < 4; ++n) acc[m][n] = MFMA16(af[m], bf[n], acc[m][n]);
    __syncthreads();
  }

  const int r0 = (lane >> 4) << 2;
  const int c0 = lane & 15;
  if (Cb) {
    #pragma unroll
    for (int m = 0; m < 4; ++m)
      #pragma unroll
      for (int n = 0; n < 4; ++n)
        #pragma unroll
        for (int j = 0; j < 4; ++j) {
          const size_t row = brow + (wr << 6) + m * 16 + r0 + j;
          const size_t col = bcol + (wc << 6) + n * 16 + c0;
          Cb[row * N + col] = f2bf(acc[m][n][j]);
        }
  } else {
    #pragma unroll
    for (int m = 0; m < 4; ++m)
      #pragma unroll
      for (int n = 0; n < 4; ++n)
        #pragma unroll
        for (int j = 0; j < 4; ++j) {
          const size_t row = brow + (wr << 6) + m * 16 + r0 + j;
          const size_t col = bcol + (wc << 6) + n * 16 + c0;
          Cf[row * N + col] = acc[m][n][j] + bias[col];
        }
  }
}

// ---------------- flash attention v2 ----------------
// Swapped QK^T: s = mfma(K_frag, Q_frag) -> S^T[kv][q]; lane owns ONE q column
// (q = lane&15), so softmax max/sum = 15 in-reg ops + 2 shfl. PV computed as
// O^T = mfma(V^T_frag, P^T_frag) so m/l/alpha stay per-lane scalars.
// P^T -> A/B re-layout via per-wave chunk-major LDS buffer Ps[8][16][8u16]
// (2-way bank conflicts only). K/V tiles double-buffered with counted vmcnt.

template <bool MASK>
__device__ __forceinline__ void attn_tile(
    const unsigned short* __restrict__ K, const unsigned short* __restrict__ V,
    unsigned short* __restrict__ PsW,
    shortx8 qf0, shortx8 qf1, int lane, int kv0, int qrow,
    float& m_run, float& l_run, f32x4* acc) {
  const f32x4 z = {0.f, 0.f, 0.f, 0.f};
  const int ql = lane & 15, g = lane >> 4, swz = lane & 7;

  f32x4 s[4];
  #pragma unroll
  for (int f = 0; f < 4; ++f) {
    const int r = 16 * f + ql;
    shortx8 k0 = *(const shortx8*)&K[r * 64 + (((g) ^ swz) << 3)];
    shortx8 k1 = *(const shortx8*)&K[r * 64 + (((4 + g) ^ swz) << 3)];
    f32x4 t = MFMA16(k0, qf0, z);
    s[f] = MFMA16(k1, qf1, t);
  }

  float sv[16];
  float mx = -3.389e38f;
  #pragma unroll
  for (int f = 0; f < 4; ++f)
    #pragma unroll
    for (int j = 0; j < 4; ++j) {
      float v = s[f][j] * 0.125f;
      if (MASK && (kv0 + 16 * f + 4 * g + j > qrow)) v = -__builtin_inff();
      sv[f * 4 + j] = v;
      mx = fmaxf(mx, v);
    }
  mx = fmaxf(mx, __shfl_xor(mx, 16));
  mx = fmaxf(mx, __shfl_xor(mx, 32));
  const float nm = fmaxf(m_run, mx);
  const float alpha = __expf(m_run - nm);  // first tile: exp(-inf)=0, acc already 0
  float rsum = 0.f;
  unsigned short pb[16];
  #pragma unroll
  for (int i = 0; i < 16; ++i) {
    float p = __expf(sv[i] - nm);
    rsum += p;
    pb[i] = f2bf(p);
  }
  rsum += __shfl_xor(rsum, 16);
  rsum += __shfl_xor(rsum, 32);
  m_run = nm;
  l_run = l_run * alpha + rsum;
  #pragma unroll
  for (int c = 0; c < 4; ++c) acc[c] *= alpha;

  // P^T quads -> Ps chunk-major: lane holds kv {16f+4g+j}; logical chunk lc=2f+(g>>1)
  #pragma unroll
  for (int f = 0; f < 4; ++f) {
    shortx4 q4;
    q4[0] = (short)pb[4 * f + 0]; q4[1] = (short)pb[4 * f + 1];
    q4[2] = (short)pb[4 * f + 2]; q4[3] = (short)pb[4 * f + 3];
    *(shortx4*)&PsW[(2 * f + (g >> 1)) * 128 + ql * 8 + (g & 1) * 4] = q4;
  }
  __builtin_amdgcn_sched_barrier(0);  // keep same-wave DS write before read
  // B-operand frags: k-half h needs kv 32h+8g..+7 -> logical chunk 4h+g
  shortx8 pf0 = *(const shortx8*)&PsW[(g) * 128 + ql * 8];
  shortx8 pf1 = *(const shortx8*)&PsW[(4 + g) * 128 + ql * 8];
  #pragma unroll
  for (int c = 0; c < 4; ++c) {
    const int r = 16 * c + ql;
    shortx8 v0 = *(const shortx8*)&V[r * 64 + (((g) ^ swz) << 3)];
    shortx8 v1 = *(const shortx8*)&V[r * 64 + (((4 + g) ^ swz) << 3)];
    acc[c] = MFMA16(v0, pf0, acc[c]);
    acc[c] = MFMA16(v1, pf1, acc[c]);
  }
}

__global__ __launch_bounds__(256) void attn_fwd(
    const unsigned short* __restrict__ qkv, const unsigned short* __restrict__ vT,
    unsigned short* __restrict__ att) {
  __shared__ unsigned short Ks[2][4096];
  __shared__ unsigned short Vt[2][4096];
  __shared__ unsigned short Ps[4][1024];

  const int tid = threadIdx.x;
  const int lane = tid & 63;
  const int w = tid >> 6;
  const int pair = blockIdx.x, h = blockIdx.y, b = blockIdx.z;
  const int qtA = pair, qtB = 31 - pair;  // (qtA+1)+(qtB+1) = 33 tiles: balanced
  const int ql = lane & 15, g = lane >> 4;
  const int qrowA = qtA * 64 + w * 16 + ql;
  const int qrowB = qtB * 64 + w * 16 + ql;
  unsigned short* PsW = &Ps[w][0];

  // Q fragments (usable as MFMA B-operand): Q[q=lane&15][d=(lane>>4)*8+e]
  const unsigned short* qpA = qkv + ((size_t)(b * 2048 + qrowA)) * 3072 + h * 64 + (g << 3);
  const unsigned short* qpB = qkv + ((size_t)(b * 2048 + qrowB)) * 3072 + h * 64 + (g << 3);
  const shortx8 qfA0 = *(const shortx8*)qpA;
  const shortx8 qfA1 = *(const shortx8*)(qpA + 32);
  const shortx8 qfB0 = *(const shortx8*)qpB;
  const shortx8 qfB1 = *(const shortx8*)(qpB + 32);

  f32x4 z = {0.f, 0.f, 0.f, 0.f};
  f32x4 accA[4], accB[4];
  #pragma unroll
  for (int c = 0; c < 4; ++c) { accA[c] = z; accB[c] = z; }
  float mA = -__builtin_inff(), lA = 0.f, mB = -__builtin_inff(), lB = 0.f;

  // staging: thread t -> row t>>3 (+32 second half), src 16B chunk (t&7)^(row&7)
  const int srow = tid >> 3;
  const int sch = ((tid & 7) ^ (srow & 7)) << 3;
  const unsigned short* kb = qkv + ((size_t)(b * 2048 + srow)) * 3072 + 1024 + h * 64 + sch;
  const unsigned short* vb = vT + ((size_t)(h * 64 + srow)) * 4096 + b * 2048 + sch;

  #define STAGE(kv0_, bufi_)                                        \
    do {                                                            \
      unsigned short* Kd = &Ks[bufi_][w * 512];                     \
      unsigned short* Vd = &Vt[bufi_][w * 512];                     \
      gload16(kb + (size_t)(kv0_) * 3072, Kd);                      \
      gload16(kb + (size_t)((kv0_) + 32) * 3072, Kd + 2048);        \
      gload16(vb + (kv0_), Vd);                                     \
      gload16(vb + (size_t)32 * 4096 + (kv0_), Vd + 2048);          \
    } while (0)

  int buf = 0;
  STAGE(0, 0);
  for (int kvt = 0; kvt <= qtB; ++kvt) {
    const bool last = (kvt == qtB);
    if (!last) STAGE((kvt + 1) * 64, buf ^ 1);
    if (last) asm volatile("s_waitcnt vmcnt(0)" ::: "memory");
    else      asm volatile("s_waitcnt vmcnt(4)" ::: "memory");
    __builtin_amdgcn_sched_barrier(0);
    __builtin_amdgcn_s_barrier();
    __builtin_amdgcn_sched_barrier(0);
    const unsigned short* K = Ks[buf];
    const unsigned short* V = Vt[buf];
    const int kv0 = kvt * 64;
    if (kvt < qtA)
      attn_tile<false>(K, V, PsW, qfA0, qfA1, lane, kv0, qrowA, mA, lA, accA);
    else if (kvt == qtA)
      attn_tile<true>(K, V, PsW, qfA0, qfA1, lane, kv0, qrowA, mA, lA, accA);
    if (kvt < qtB)
      attn_tile<false>(K, V, PsW, qfB0, qfB1, lane, kv0, qrowB, mB, lB, accB);
    else
      attn_tile<true>(K, V, PsW, qfB0, qfB1, lane, kv0, qrowB, mB, lB, accB);
    __builtin_amdgcn_sched_barrier(0);
    __builtin_amdgcn_s_barrier();
    __builtin_amdgcn_sched_barrier(0);
    buf ^= 1;
  }
  #undef STAGE

  // epilogue: acc[c][j] = O^T[d=16c+4g+j][q=qrow]; pack 4 consecutive d -> 8B store
  const float invA = 1.f / lA;
  const float invB = 1.f / lB;
  unsigned short* oA = att + ((size_t)(b * 2048 + qrowA)) * 1024 + h * 64 + 4 * g;
  unsigned short* oB = att + ((size_t)(b * 2048 + qrowB)) * 1024 + h * 64 + 4 * g;
  #pragma unroll
  for (int c = 0; c < 4; ++c) {
    shortx4 a, bb;
    #pragma unroll
    for (int j = 0; j < 4; ++j) {
      a[j] = (short)f2bf(accA[c][j] * invA);
      bb[j] = (short)f2bf(accB[c][j] * invB);
    }
    *(shortx4*)&oA[16 * c] = a;
    *(shortx4*)&oB[16 * c] = bb;
  }
}

// ---------------- launch ----------------
extern "C" void kernel_launch(void* const* d_in, const int* in_sizes, int n_in,
                              void* d_out, int out_size, void* d_ws, size_t ws_size,
                              hipStream_t stream) {
  const float* x  = (const float*)d_in[0];
  const float* Wq = (const float*)d_in[1];
  const float* Wk = (const float*)d_in[2];
  const float* Wv = (const float*)d_in[3];
  const float* Wp = (const float*)d_in[4];
  const float* bp = (const float*)d_in[5];

  char* ws = (char*)d_ws;
  unsigned short* xb    = (unsigned short*)(ws);                        //  8 MB [4096][1024]
  unsigned short* wqkvT = (unsigned short*)(ws + (size_t)8  * 1048576); //  6 MB [3072][1024]
  unsigned short* wpT   = (unsigned short*)(ws + (size_t)14 * 1048576); //  2 MB [1024][1024]
  unsigned short* qkv   = (unsigned short*)(ws + (size_t)16 * 1048576); // 24 MB [4096][3072]
  unsigned short* vT    = (unsigned short*)(ws + (size_t)40 * 1048576); //  8 MB [1024][4096]
  unsigned short* att   = (unsigned short*)(ws + (size_t)48 * 1048576); //  8 MB [4096][1024]

  cvt_x<<<dim3(4096), dim3(256), 0, stream>>>(x, xb, 1048576);
  transpose_w<<<dim3(32, 32), dim3(256), 0, stream>>>(Wq, wqkvT);
  transpose_w<<<dim3(32, 32), dim3(256), 0, stream>>>(Wk, wqkvT + (size_t)1048576);
  transpose_w<<<dim3(32, 32), dim3(256), 0, stream>>>(Wv, wqkvT + (size_t)2097152);
  transpose_w<<<dim3(32, 32), dim3(256), 0, stream>>>(Wp, wpT);
  gemm_bt<<<dim3(24, 32), dim3(256), 0, stream>>>(xb, wqkvT, qkv, nullptr, nullptr,
                                                  4096, 3072, 1024);
  transpose_v<<<dim3(16, 64), dim3(256), 0, stream>>>(qkv, vT);
  attn_fwd<<<dim3(16, 16, 2), dim3(256), 0, stream>>>(qkv, vT, att);
  gemm_bt<<<dim3(8, 32), dim3(256), 0, stream>>>(att, wpT, nullptr, (float*)d_out, bp,
                                                 4096, 1024, 1024);
}